// Round 12
// baseline (171.613 us; speedup 1.0000x reference)
//
#include <hip/hip_runtime.h>
#include <hip/hip_bf16.h>

// SupervisedGraphSage forward. fp32 device buffers; bf16 MFMA internally.
//   z  = x @ W1^T                        [N, D]  (K1)
//   h1 = leaky((z[neigh1].sum + z)/6)    [N, D]  (K2, only referenced rows)
//   h2 = leaky((h1[neigh2].sum+h1[nodes])/11 @ W2^T); out = h2 @ Wc^T  (K3 fused)
//
// R12: K1 fully async-staged. Both A (raw fp32, source-swizzled) and B (bf16,
// pre-swizzled) go global_load_lds -> double-buffered LDS with counted
// vmcnt(4); A converts to bf16 at fragment-read time. Removes the reg-staging
// round-trip whose ~900cy HBM wait exceeded one K-step of cover (R7-R11:
// latency-bound at 2.4-3 TB/s, MfmaUtil<=11%, VGPRs exactly at the 128 cap).
// BK=32, LDS 64KB (2 blocks/CU), proven LDS epilogue reuses the same 64KB.

#define NN 100000
#define FF 512
#define DD 256
#define BB 16384
#define CC 40

typedef __attribute__((ext_vector_type(8))) short bf16x8;
typedef __attribute__((ext_vector_type(4))) float f32x4;
typedef unsigned short u16;
typedef unsigned int u32;
typedef __attribute__((ext_vector_type(4))) u32 u32x4;

__device__ __forceinline__ float bf_lo(u32 u) { u32 v = u << 16; float f; __builtin_memcpy(&f, &v, 4); return f; }
__device__ __forceinline__ float bf_hi(u32 u) { u32 v = u & 0xffff0000u; float f; __builtin_memcpy(&f, &v, 4); return f; }
__device__ __forceinline__ float2 bf2f(u32 u) { return make_float2(bf_lo(u), bf_hi(u)); }
__device__ __forceinline__ float asf(u32 u) { float f; __builtin_memcpy(&f, &u, 4); return f; }
__device__ __forceinline__ u32 packbf2(float a, float b) {
  __hip_bfloat162 h = __float22bfloat162_rn(make_float2(a, b));
  u32 u; __builtin_memcpy(&u, &h, 4); return u;
}
__device__ __forceinline__ u16 fbits(float v) {
  __hip_bfloat16 h = __float2bfloat16(v);
  u16 u; __builtin_memcpy(&u, &h, 2); return u;
}
__device__ __forceinline__ float lrelu(float v) { return v >= 0.f ? v : 0.2f * v; }
// [R][64]-bf16 tile: byte offset of chunk c in row r, XOR-swizzled (G4). K3 use.
__device__ __forceinline__ int swz(int r, int c) { return r * 128 + ((c ^ (r & 7)) << 4); }
// direct global->LDS 16B copy (dest = wave-uniform base + lane*16)
__device__ __forceinline__ void gld_lds16(const u16* g, void* l) {
  __builtin_amdgcn_global_load_lds((const __attribute__((address_space(1))) unsigned int*)g,
                                   (__attribute__((address_space(3))) unsigned int*)l, 16, 0, 0);
}
__device__ __forceinline__ void gld_lds16f(const float* g, void* l) {
  __builtin_amdgcn_global_load_lds((const __attribute__((address_space(1))) unsigned int*)g,
                                   (__attribute__((address_space(3))) unsigned int*)l, 16, 0, 0);
}

// ---------------------------------------------------------------- K0
// W1 -> bf16, 4-chunk-group swizzle (^r^(r>>2), matches K1's BK=32 B-reads).
// W2/Wc -> bf16, 8-chunk-group swizzle (^(r&7)) for K3. Also zero flags.
__global__ __launch_bounds__(256) void k0_cvt(
    const float* __restrict__ W1, const float* __restrict__ W2, const float* __restrict__ Wc,
    u16* __restrict__ w1b, u16* __restrict__ w2b, u16* __restrict__ wcb,
    u32* __restrict__ flagw)
{
  const int i = blockIdx.x * 256 + threadIdx.x;
  if (i < 25024) flagw[i] = 0;   // 100096 flag bytes
  if (i < 16384) {               // W1 [256][512]: r = i>>6, 16B-chunk cc = i&63
    const int r = i >> 6, cc = i & 63;
    const int lc = (cc & ~3) | ((cc ^ r ^ (r >> 2)) & 3);
    const float* s = W1 + (u32)r * 512 + (u32)lc * 8;
    const float4 v0 = *(const float4*)s;
    const float4 v1 = *(const float4*)(s + 4);
    uint4 o;
    o.x = packbf2(v0.x, v0.y); o.y = packbf2(v0.z, v0.w);
    o.z = packbf2(v1.x, v1.y); o.w = packbf2(v1.z, v1.w);
    *(uint4*)(w1b + (u32)r * 512 + (u32)cc * 8) = o;
    return;
  }
  const float* src; u16* dst; int r, cc;
  if (i < 24576)      { int j = i - 16384; src = W2; dst = w2b; r = j >> 5; cc = j & 31; }
  else if (i < 25856) { int j = i - 24576; src = Wc; dst = wcb; r = j >> 5; cc = j & 31; }
  else return;
  const int g = cc >> 3, cp = cc & 7;
  const float* s = src + (u32)r * 256 + g * 64 + (u32)(cp ^ (r & 7)) * 8;
  const float4 v0 = *(const float4*)s;
  const float4 v1 = *(const float4*)(s + 4);
  uint4 o;
  o.x = packbf2(v0.x, v0.y); o.y = packbf2(v0.z, v0.w);
  o.z = packbf2(v1.x, v1.y); o.w = packbf2(v1.z, v1.w);
  *(uint4*)(dst + (u32)r * 256 + g * 64 + cp * 8) = o;
}

// ---------------------------------------------------------------- K0b
__global__ __launch_bounds__(256) void k0b_flags(
    const int* __restrict__ nodes, const int* __restrict__ neigh2,
    unsigned char* __restrict__ flags)
{
  const int i = blockIdx.x * 256 + threadIdx.x;
  int idx;
  if (i < BB) idx = nodes[i];
  else if (i < BB + BB * 10) idx = neigh2[i - BB];
  else return;
  flags[idx] = 1;
}

// ---------------------------------------------------------------- K1
// z = x @ W1^T. BM=128, BN=256, BK=32, 16 steps, 512 thr = 8 waves (2Mx4N),
// wave tile 64x64. LDS: A-fp32 dbuf @0/@16384 (16KB each, [128r][128B],
// source-swizzled qchunks), B-bf16 dbuf @32768/@49152 ([256r][64B],
// pre-swizzled in w1b). 4 gld_lds/thread/step, vmcnt(4) counted.
__global__ __launch_bounds__(512, 4) void k1_gemm(
    const float* __restrict__ x, const u16* __restrict__ w1b, u16* __restrict__ z)
{
  __shared__ __align__(16) unsigned char lds[65536];

  const int t = threadIdx.x;
  const int rowBase = blockIdx.x * 128;
  const int lane = t & 63, w = t >> 6;
  const int wm = w >> 2, wn = w & 3;
  const int lr = lane & 15, kg = lane >> 4;

  // A staging source: issue i covers rows i*64 + w*8 + (lane>>3); the lane's
  // 16B = logical qchunk (lane&7)^(row&7) = (lane&7)^(lane>>3) (src-swizzle).
  const u32 lq = (u32)((lane & 7) ^ (lane >> 3));
  u32 xoff[2];
#pragma unroll
  for (int i = 0; i < 2; ++i) {
    int row = rowBase + i * 64 + w * 8 + (lane >> 3);
    if (row > NN - 1) row = NN - 1;
    xoff[i] = (u32)row * FF + lq * 4;
  }
  // B staging source: issue i covers rows i*128 + w*16 + (lane>>2), phys
  // chunk lane&3 (swizzle pre-baked in w1b by K0).
  u32 boff[2];
#pragma unroll
  for (int i = 0; i < 2; ++i)
    boff[i] = (u32)(i * 128 + w * 16 + (lane >> 2)) * FF + (u32)(lane & 3) * 8;

  // fragment read addresses (add (ks&1)*16384 at use)
  int aR[4][2];
#pragma unroll
  for (int m = 0; m < 4; ++m) {
    const int row = wm * 64 + m * 16 + lr;
#pragma unroll
    for (int j = 0; j < 2; ++j) {
      const int phys = (kg * 2 + j) ^ (row & 7);
      aR[m][j] = row * 128 + phys * 16;
    }
  }
  int bR[4];
#pragma unroll
  for (int n = 0; n < 4; ++n) {
    const int row = wn * 64 + n * 16 + lr;
    const int phys = (kg ^ row ^ (row >> 2)) & 3;
    bR[n] = 32768 + row * 64 + phys * 16;
  }

  f32x4 acc[4][4];
#pragma unroll
  for (int m = 0; m < 4; ++m)
#pragma unroll
    for (int n = 0; n < 4; ++n) acc[m][n] = (f32x4)0.0f;

#define K1_ISSUE(ks_) do {                                                   \
    unsigned char* ab = lds + ((ks_) & 1) * 16384 + w * 1024;                \
    unsigned char* bb = lds + 32768 + ((ks_) & 1) * 16384 + w * 1024;        \
    gld_lds16f(x + xoff[0] + (u32)(ks_) * 32, ab);                           \
    gld_lds16f(x + xoff[1] + (u32)(ks_) * 32, ab + 8192);                    \
    gld_lds16(w1b + boff[0] + (u32)(ks_) * 32, bb);                          \
    gld_lds16(w1b + boff[1] + (u32)(ks_) * 32, bb + 8192);                   \
  } while (0)

  // prologue: steps 0 and 1 in flight (8 loads/thread)
  K1_ISSUE(0);
  K1_ISSUE(1);

#pragma unroll 2
  for (int ks = 0; ks < 16; ++ks) {
    if (ks < 15) asm volatile("s_waitcnt vmcnt(4)" ::: "memory");  // step ks landed
    else         asm volatile("s_waitcnt vmcnt(0)" ::: "memory");
    __builtin_amdgcn_sched_barrier(0);
    __builtin_amdgcn_s_barrier();            // all waves' step-ks data in LDS
    __builtin_amdgcn_sched_barrier(0);

    const int bo = (ks & 1) * 16384;
    u32x4 alo[4], ahi[4]; bf16x8 bv[4];
#pragma unroll
    for (int m = 0; m < 4; ++m) {
      alo[m] = *(const u32x4*)(lds + aR[m][0] + bo);
      ahi[m] = *(const u32x4*)(lds + aR[m][1] + bo);
    }
#pragma unroll
    for (int n = 0; n < 4; ++n) bv[n] = *(const bf16x8*)(lds + bR[n] + bo);
    asm volatile("s_waitcnt lgkmcnt(0)" ::: "memory");
    __builtin_amdgcn_sched_barrier(0);
    __builtin_amdgcn_s_barrier();            // all waves done reading buf[ks&1]
    __builtin_amdgcn_sched_barrier(0);
    if (ks <= 13) K1_ISSUE(ks + 2);          // overwrite buf[ks&1] asynchronously
    __builtin_amdgcn_sched_barrier(0);

    // cvt A fp32 -> bf16 frags, then MFMA (swapped operands: lane holds
    // 4 consecutive z-cols of one z-row)
    bf16x8 av[4];
#pragma unroll
    for (int m = 0; m < 4; ++m) {
      u32x4 p;
      p[0] = packbf2(asf(alo[m][0]), asf(alo[m][1]));
      p[1] = packbf2(asf(alo[m][2]), asf(alo[m][3]));
      p[2] = packbf2(asf(ahi[m][0]), asf(ahi[m][1]));
      p[3] = packbf2(asf(ahi[m][2]), asf(ahi[m][3]));
      av[m] = *(bf16x8*)&p;
    }
#pragma unroll
    for (int m = 0; m < 4; ++m)
#pragma unroll
      for (int n = 0; n < 4; ++n)
        acc[m][n] = __builtin_amdgcn_mfma_f32_16x16x32_bf16(bv[n], av[m], acc[m][n], 0, 0, 0);
  }
#undef K1_ISSUE

  // ---- epilogue via LDS (proven R11): swizzled [128][256]bf16 tile @0 ----
  __syncthreads();   // all LDS traffic drained; whole 64KB reusable
#pragma unroll
  for (int m = 0; m < 4; ++m) {
    const int zr = wm * 64 + m * 16 + lr;          // 0..127
#pragma unroll
    for (int n = 0; n < 4; ++n) {
      const int zc = wn * 64 + n * 16 + kg * 4;    // 4 consecutive cols
      uint2 o;
      o.x = packbf2(acc[m][n][0], acc[m][n][1]);
      o.y = packbf2(acc[m][n][2], acc[m][n][3]);
      const int ch = zc >> 3;
      const int pch = (ch & 24) | ((ch ^ (zr & 7)) & 7);
      *(uint2*)(lds + zr * 512 + pch * 16 + (zc & 7) * 2) = o;
    }
  }
  __syncthreads();
  // dense store: 32 lanes cover one 512B row; 1KB contiguous per instruction
#pragma unroll
  for (int i = 0; i < 8; ++i) {
    const int id = t + i * 512;
    const int rr = id >> 5, cc = id & 31;
    const int pch = (cc & 24) | ((cc ^ (rr & 7)) & 7);
    const uint4 v = *(const uint4*)(lds + rr * 512 + pch * 16);
    *(uint4*)(z + (u32)(rowBase + rr) * DD + cc * 8) = v;
  }
}

// ---------------------------------------------------------------- K2
// h1 = leaky((z[neigh1].sum + z)/6), only for rows layer 2 reads.
__global__ __launch_bounds__(256) void k2_agg1(
    const u16* __restrict__ z, const int* __restrict__ neigh1, u16* __restrict__ h1,
    const unsigned char* __restrict__ flags)
{
  const int t = threadIdx.x;
  const int row = blockIdx.x * 8 + (t >> 5);
  if (!flags[row]) return;   // half-wave uniform; no barriers in this kernel
  const int ch = t & 31;
  const u32 o0 = (u32)row * DD + ch * 8;
  uint4 a = *(const uint4*)(z + o0);
  float2 s0 = bf2f(a.x), s1 = bf2f(a.y), s2 = bf2f(a.z), s3 = bf2f(a.w);
#pragma unroll
  for (int j = 0; j < 5; ++j) {
    const int idx = neigh1[row * 5 + j];
    const uint4 v = *(const uint4*)(z + (u32)idx * DD + ch * 8);
    s0.x += bf_lo(v.x); s0.y += bf_hi(v.x);
    s1.x += bf_lo(v.y); s1.y += bf_hi(v.y);
    s2.x += bf_lo(v.z); s2.y += bf_hi(v.z);
    s3.x += bf_lo(v.w); s3.y += bf_hi(v.w);
  }
  const float sc = 1.0f / 6.0f;
  uint4 o;
  o.x = packbf2(lrelu(s0.x * sc), lrelu(s0.y * sc));
  o.y = packbf2(lrelu(s1.x * sc), lrelu(s1.y * sc));
  o.z = packbf2(lrelu(s2.x * sc), lrelu(s2.y * sc));
  o.w = packbf2(lrelu(s3.x * sc), lrelu(s3.y * sc));
  *(uint4*)(h1 + o0) = o;
}

// ---------------------------------------------------------------- K3 (fused layer2 + scores)
__global__ __launch_bounds__(512, 2) void k3_fused(
    const u16* __restrict__ h1, const u16* __restrict__ w2b, const u16* __restrict__ wcb,
    const int* __restrict__ nodes, const int* __restrict__ neigh2, float* __restrict__ out)
{
  // 0: A 8KB | 8192: B 32KB | 40960: Wc 24KB. After loop: 0..32KB = h2 tile.
  __shared__ __align__(16) unsigned char lds[65536];

  const int t = threadIdx.x;
  const int rowBase = blockIdx.x * 64;
  const int lane = t & 63, w = t >> 6;
  const int wm = w >> 2, wn = w & 3;
  const int lr = lane & 15, kg = lane >> 4;

#pragma unroll
  for (int i = 0; i < 3; ++i) {
    const int id = t + i * 512;
    uint4 v = make_uint4(0u, 0u, 0u, 0u);
    if (id < 1280) v = *(const uint4*)(wcb + (u32)id * 8);
    *(uint4*)(lds + 40960 + id * 16) = v;
  }

  const int r = t >> 3, c = t & 7;
  const int b = rowBase + r;
  u32 offA[11];
  offA[0] = (u32)nodes[b] * DD + (u32)c * 8;
#pragma unroll
  for (int j = 0; j < 10; ++j)
    offA[1 + j] = (u32)neigh2[b * 10 + j] * DD + (u32)c * 8;
  const int aW = swz(r, c);

  const u32 bofs = (u32)(w * 8 + (lane >> 3)) * DD + (u32)(lane & 7) * 8;
  unsigned char* bl0 = lds + 8192 + w * 1024;

  int aA[2][2], bA[2][4];
#pragma unroll
  for (int kk = 0; kk < 2; ++kk) {
    const int cb = kk * 4 + kg;
#pragma unroll
    for (int m = 0; m < 2; ++m) aA[kk][m] = swz(wm * 32 + m * 16 + lr, cb);
#pragma unroll
    for (int n = 0; n < 4; ++n) bA[kk][n] = 8192 + swz(wn * 64 + n * 16 + lr, cb);
  }

  f32x4 acc[2][4];
#pragma unroll
  for (int m = 0; m < 2; ++m)
#pragma unroll
    for (int n = 0; n < 4; ++n) acc[m][n] = (f32x4)0.0f;

  uint4 ag[11];
#pragma unroll
  for (int j = 0; j < 11; ++j) ag[j] = *(const uint4*)(h1 + offA[j]);

  for (int ks = 0; ks < 4; ++ks) {
    if (ks) __builtin_amdgcn_s_barrier();
    {
      float2 s0 = make_float2(0.f, 0.f), s1 = make_float2(0.f, 0.f);
      float2 s2 = make_float2(0.f, 0.f), s3 = make_float2(0.f, 0.f);
#pragma unroll
      for (int j = 0; j < 11; ++j) {
        s0.x += bf_lo(ag[j].x); s0.y += bf_hi(ag[j].x);
        s1.x += bf_lo(ag[j].y); s1.y += bf_hi(ag[j].y);
        s2.x += bf_lo(ag[j].z); s2.y += bf_hi(ag[j].z);
        s3.x += bf_lo(ag[j].w); s3.y += bf_hi(ag[j].w);
      }
      const float sc = 1.0f / 11.0f;
      uint4 o;
      o.x = packbf2(s0.x * sc, s0.y * sc);
      o.y = packbf2(s1.x * sc, s1.y * sc);
      o.z = packbf2(s2.x * sc, s2.y * sc);
      o.w = packbf2(s3.x * sc, s3.y * sc);
      *(uint4*)(lds + aW) = o;
    }
#pragma unroll
    for (int i = 0; i < 4; ++i)
      gld_lds16(w2b + bofs + (u32)i * 64 * DD + (u32)ks * 64, bl0 + i * 8192);
    __syncthreads();
    if (ks < 3) {
#pragma unroll
      for (int j = 0; j < 11; ++j)
        ag[j] = *(const uint4*)(h1 + offA[j] + (u32)(ks + 1) * 64);
    }
    __builtin_amdgcn_sched_barrier(0);
#pragma unroll
    for (int kk = 0; kk < 2; ++kk) {
      bf16x8 av[2], bv[4];
#pragma unroll
      for (int m = 0; m < 2; ++m) av[m] = *(const bf16x8*)(lds + aA[kk][m]);
#pragma unroll
      for (int n = 0; n < 4; ++n) bv[n] = *(const bf16x8*)(lds + bA[kk][n]);
#pragma unroll
      for (int m = 0; m < 2; ++m)
#pragma unroll
        for (int n = 0; n < 4; ++n)
          acc[m][n] = __builtin_amdgcn_mfma_f32_16x16x32_bf16(av[kk == 0 ? m : m], bv[n], acc[m][n], 0, 0, 0);
    }
  }

  __syncthreads();
#pragma unroll
  for (int m = 0; m < 2; ++m) {
#pragma unroll
    for (int j = 0; j < 4; ++j) {
      const int row = wm * 32 + m * 16 + kg * 4 + j;
#pragma unroll
      for (int n = 0; n < 4; ++n) {
        const int col = wn * 64 + n * 16 + lr;
        const int ch = col >> 3;
        const int pch = (ch & 24) | ((ch ^ row) & 7);
        *(u16*)(lds + row * 512 + pch * 16 + (col & 7) * 2) = fbits(lrelu(acc[m][n][j]));
      }
    }
  }
  __syncthreads();

  if (w < 4) {
    f32x4 acc2[3];
#pragma unroll
    for (int n = 0; n < 3; ++n) acc2[n] = (f32x4)0.0f;
    const int arow = w * 16 + lr;
#pragma unroll
    for (int ks2 = 0; ks2 < 8; ++ks2) {
      const int chb = ks2 * 4 + kg;
      const int pchA = (chb & 24) | ((chb ^ arow) & 7);
      const bf16x8 a = *(const bf16x8*)(lds + arow * 512 + pchA * 16);
#pragma unroll
      for (int n = 0; n < 3; ++n) {
        const int brow = n * 16 + lr;
        const int pchB = (chb & 24) | ((chb ^ brow) & 7);
        const bf16x8 bb = *(const bf16x8*)(lds + 40960 + brow * 512 + pchB * 16);
        acc2[n] = __builtin_amdgcn_mfma_f32_16x16x32_bf16(a, bb, acc2[n], 0, 0, 0);
      }
    }
#pragma unroll
    for (int n = 0; n < 3; ++n) {
      const int col = n * 16 + lr;
      if (col < CC) {
#pragma unroll
        for (int j = 0; j < 4; ++j) {
          const int rr = rowBase + w * 16 + kg * 4 + j;
          out[(u32)rr * CC + col] = acc2[n][j];
        }
      }
    }
  }
}

extern "C" void kernel_launch(void* const* d_in, const int* in_sizes, int n_in,
                              void* d_out, int out_size, void* d_ws, size_t ws_size,
                              hipStream_t stream) {
  const float* x    = (const float*)d_in[0];
  const float* W1   = (const float*)d_in[1];
  const float* W2   = (const float*)d_in[2];
  const float* Wc   = (const float*)d_in[3];
  const int* nodes  = (const int*)d_in[4];
  const int* neigh1 = (const int*)d_in[5];
  const int* neigh2 = (const int*)d_in[6];

  u16* z   = (u16*)d_ws;                     // 100096*256 bf16
  u16* h1  = z + (size_t)100096 * 256;       // 100096*256 bf16
  u16* w1b = h1 + (size_t)100096 * 256;      // 256x512 bf16 (4-chunk swizzled)
  u16* w2b = w1b + (size_t)256 * 512;        // 256x256 bf16 (8-chunk swizzled)
  u16* wcb = w2b + (size_t)256 * 256;        // 40x256 bf16 (8-chunk swizzled)
  u32* flagw = (u32*)(wcb + (size_t)40 * 256);  // 25024 u32 = 100096 flag bytes
  unsigned char* flags = (unsigned char*)flagw;

  k0_cvt<<<dim3(101), dim3(256), 0, stream>>>(W1, W2, Wc, w1b, w2b, wcb, flagw);
  k0b_flags<<<dim3(704), dim3(256), 0, stream>>>(nodes, neigh2, flags);
  k1_gemm<<<dim3(782), dim3(512), 0, stream>>>(x, w1b, z);
  k2_agg1<<<dim3(12500), dim3(256), 0, stream>>>(z, neigh1, h1, flags);
  k3_fused<<<dim3(256), dim3(512), 0, stream>>>(h1, w2b, wcb, nodes, neigh2, (float*)d_out);
}

// Round 13
// 136.179 us; speedup vs baseline: 1.2602x; 1.2602x over previous
//
#include <hip/hip_runtime.h>
#include <hip/hip_bf16.h>

// SupervisedGraphSage forward. fp32 device buffers; bf16 MFMA internally.
//   z  = x @ W1^T                        [N, D]  (K1)
//   h1 = leaky((z[neigh1].sum + z)/6)    [N, D]  (K2, only referenced rows)
//   h2 = leaky((h1[neigh2].sum+h1[nodes])/11 @ W2^T); out = h2 @ Wc^T  (K3 fused)
//
// R13 = R11 champion (145.6us) + ONE isolated change: NT dropped from x loads.
// R12 counter evidence: FETCH 118MB < x's 205MB -> x is partially L3-resident
// across graph replays; NT forbids that, forcing full ~900cy HBM latency on
// the A-path whose write-stall is K1's diagnosed bottleneck (latency-bound at
// 2.4-3TB/s, MfmaUtil<=11%). R12 lesson: full-LDS staging with lgkmcnt(0)
// drains convoys the pipeline (128us) — keep R11's compiler-scheduled reads.

#define NN 100000
#define FF 512
#define DD 256
#define BB 16384
#define CC 40

typedef __attribute__((ext_vector_type(8))) short bf16x8;
typedef __attribute__((ext_vector_type(4))) float f32x4;
typedef unsigned short u16;
typedef unsigned int u32;
typedef __attribute__((ext_vector_type(4))) u32 u32x4;

__device__ __forceinline__ float bf_lo(u32 u) { u32 v = u << 16; float f; __builtin_memcpy(&f, &v, 4); return f; }
__device__ __forceinline__ float bf_hi(u32 u) { u32 v = u & 0xffff0000u; float f; __builtin_memcpy(&f, &v, 4); return f; }
__device__ __forceinline__ float2 bf2f(u32 u) { return make_float2(bf_lo(u), bf_hi(u)); }
__device__ __forceinline__ float asf(u32 u) { float f; __builtin_memcpy(&f, &u, 4); return f; }
__device__ __forceinline__ u32 packbf2(float a, float b) {
  __hip_bfloat162 h = __float22bfloat162_rn(make_float2(a, b));
  u32 u; __builtin_memcpy(&u, &h, 4); return u;
}
__device__ __forceinline__ u16 fbits(float v) {
  __hip_bfloat16 h = __float2bfloat16(v);
  u16 u; __builtin_memcpy(&u, &h, 2); return u;
}
__device__ __forceinline__ float lrelu(float v) { return v >= 0.f ? v : 0.2f * v; }
// [R][64]-bf16 tile: byte offset of chunk c in row r, XOR-swizzled (G4).
__device__ __forceinline__ int swz(int r, int c) { return r * 128 + ((c ^ (r & 7)) << 4); }
// direct global->LDS 16B copy (dest = wave-uniform base + lane*16)
__device__ __forceinline__ void gld_lds16(const u16* g, void* l) {
  __builtin_amdgcn_global_load_lds((const __attribute__((address_space(1))) unsigned int*)g,
                                   (__attribute__((address_space(3))) unsigned int*)l, 16, 0, 0);
}
// plain cached 16B load (R13: NT removed — let x ride L3 across replays)
__device__ __forceinline__ u32x4 ld4(const float* p) {
  return *(const u32x4*)p;
}

// ---------------------------------------------------------------- K0
// fp32 weights -> bf16, chunk-swizzled storage; also zero the h1-row flags.
__global__ __launch_bounds__(256) void k0_cvt(
    const float* __restrict__ W1, const float* __restrict__ W2, const float* __restrict__ Wc,
    u16* __restrict__ w1b, u16* __restrict__ w2b, u16* __restrict__ wcb,
    u32* __restrict__ flagw)
{
  const int i = blockIdx.x * 256 + threadIdx.x;
  if (i < 25024) flagw[i] = 0;   // 100096 flag bytes
  const float* src; u16* dst; int r, cc, rowE;
  if (i < 16384)      { src = W1; dst = w1b; r = i >> 6; cc = i & 63; rowE = 512; }
  else if (i < 24576) { int j = i - 16384; src = W2; dst = w2b; r = j >> 5; cc = j & 31; rowE = 256; }
  else if (i < 25856) { int j = i - 24576; src = Wc; dst = wcb; r = j >> 5; cc = j & 31; rowE = 256; }
  else return;
  const int g = cc >> 3, cp = cc & 7;
  const float* s = src + (u32)r * rowE + g * 64 + (u32)(cp ^ (r & 7)) * 8;
  const float4 v0 = *(const float4*)s;
  const float4 v1 = *(const float4*)(s + 4);
  uint4 o;
  o.x = packbf2(v0.x, v0.y); o.y = packbf2(v0.z, v0.w);
  o.z = packbf2(v1.x, v1.y); o.w = packbf2(v1.z, v1.w);
  *(uint4*)(dst + (u32)r * rowE + g * 64 + cp * 8) = o;
}

// ---------------------------------------------------------------- K0b
// Mark h1 rows actually consumed by layer 2 (nodes + neigh2).
__global__ __launch_bounds__(256) void k0b_flags(
    const int* __restrict__ nodes, const int* __restrict__ neigh2,
    unsigned char* __restrict__ flags)
{
  const int i = blockIdx.x * 256 + threadIdx.x;
  int idx;
  if (i < BB) idx = nodes[i];
  else if (i < BB + BB * 10) idx = neigh2[i - BB];
  else return;
  flags[idx] = 1;
}

// ---------------------------------------------------------------- K1
// z = x @ W1^T. BM=128, BN=256, BK=64, 512 thr = 8 waves (2Mx4N), wave 64x64.
// A: fp32->bf16 reg-staged (cached prefetch). B: gld_lds double-buffer,
// counted vmcnt(8). Epilogue: acc -> swizzled 64KB LDS tile -> dense stores.
__global__ __launch_bounds__(512, 4) void k1_gemm(
    const float* __restrict__ x, const u16* __restrict__ w1b, u16* __restrict__ z)
{
  __shared__ __align__(16) unsigned char lds[81920];  // A 16KB @0, B0 @16384, B1 @49152

  const int t = threadIdx.x;
  const int rowBase = blockIdx.x * 128;
  const int lane = t & 63, w = t >> 6;
  const int wm = w >> 2, wn = w & 3;
  const int lr = lane & 15, kg = lane >> 4;

  u32 offA[2]; int aW[2];
#pragma unroll
  for (int i = 0; i < 2; ++i) {
    const int id = t + i * 512;
    const int r = id >> 3, c = id & 7;
    int row = rowBase + r; if (row > NN - 1) row = NN - 1;
    offA[i] = (u32)row * FF + c * 8;
    aW[i] = swz(r, c);
  }
  const u32 bofs = (u32)(w * 8 + (lane >> 3)) * FF + (u32)(lane & 7) * 8;

  int aA[2][4], bA[2][4];
#pragma unroll
  for (int kk = 0; kk < 2; ++kk) {
    const int cb = kk * 4 + kg;
#pragma unroll
    for (int m = 0; m < 4; ++m) aA[kk][m] = swz(wm * 64 + m * 16 + lr, cb);
#pragma unroll
    for (int n = 0; n < 4; ++n) bA[kk][n] = 16384 + swz(wn * 64 + n * 16 + lr, cb);
  }

  f32x4 acc[4][4];
#pragma unroll
  for (int m = 0; m < 4; ++m)
#pragma unroll
    for (int n = 0; n < 4; ++n) acc[m][n] = (f32x4)0.0f;

  u32x4 pa[2][2];
#pragma unroll
  for (int i = 0; i < 2; ++i) {
    pa[i][0] = ld4(x + offA[i]);
    pa[i][1] = ld4(x + offA[i] + 4);
  }
#pragma unroll
  for (int i = 0; i < 4; ++i)
    gld_lds16(w1b + bofs + (u32)i * 64 * FF, lds + 16384 + w * 1024 + i * 8192);

#pragma unroll
  for (int ks = 0; ks < 8; ++ks) {
    if (ks) {
      __builtin_amdgcn_s_barrier();
      __builtin_amdgcn_sched_barrier(0);
    }
#pragma unroll
    for (int i = 0; i < 2; ++i) {
      uint4 o;
      o.x = packbf2(asf(pa[i][0][0]), asf(pa[i][0][1]));
      o.y = packbf2(asf(pa[i][0][2]), asf(pa[i][0][3]));
      o.z = packbf2(asf(pa[i][1][0]), asf(pa[i][1][1]));
      o.w = packbf2(asf(pa[i][1][2]), asf(pa[i][1][3]));
      *(uint4*)(lds + aW[i]) = o;
    }
    if (ks < 7) {
#pragma unroll
      for (int i = 0; i < 2; ++i) {
        pa[i][0] = ld4(x + offA[i] + (u32)(ks + 1) * 64);
        pa[i][1] = ld4(x + offA[i] + (u32)(ks + 1) * 64 + 4);
      }
      unsigned char* bl = lds + 16384 + ((ks + 1) & 1) * 32768 + w * 1024;
#pragma unroll
      for (int i = 0; i < 4; ++i)
        gld_lds16(w1b + bofs + (u32)i * 64 * FF + (u32)(ks + 1) * 64, bl + i * 8192);
      asm volatile("s_waitcnt vmcnt(8) lgkmcnt(0)" ::: "memory");  // B[ks] landed
    } else {
      asm volatile("s_waitcnt vmcnt(0) lgkmcnt(0)" ::: "memory");
    }
    __builtin_amdgcn_sched_barrier(0);
    __builtin_amdgcn_s_barrier();
    __builtin_amdgcn_sched_barrier(0);
    const int bo = (ks & 1) * 32768;
#pragma unroll
    for (int kk = 0; kk < 2; ++kk) {
      bf16x8 av[4], bv[4];
#pragma unroll
      for (int m = 0; m < 4; ++m) av[m] = *(const bf16x8*)(lds + aA[kk][m]);
#pragma unroll
      for (int n = 0; n < 4; ++n) bv[n] = *(const bf16x8*)(lds + bA[kk][n] + bo);
      // swapped operands: lane holds 4 consecutive z-cols of one z-row
#pragma unroll
      for (int m = 0; m < 4; ++m)
#pragma unroll
        for (int n = 0; n < 4; ++n)
          acc[m][n] = __builtin_amdgcn_mfma_f32_16x16x32_bf16(bv[n], av[m], acc[m][n], 0, 0, 0);
    }
  }

  // ---- epilogue via LDS: fragments -> swizzled [128][256]bf16 tile @0 ----
  __syncthreads();   // all MFMA LDS reads drained; whole LDS reusable
#pragma unroll
  for (int m = 0; m < 4; ++m) {
    const int zr = wm * 64 + m * 16 + lr;          // 0..127
#pragma unroll
    for (int n = 0; n < 4; ++n) {
      const int zc = wn * 64 + n * 16 + kg * 4;    // 4 consecutive cols
      uint2 o;
      o.x = packbf2(acc[m][n][0], acc[m][n][1]);
      o.y = packbf2(acc[m][n][2], acc[m][n][3]);
      const int ch = zc >> 3;
      const int pch = (ch & 24) | ((ch ^ (zr & 7)) & 7);
      *(uint2*)(lds + zr * 512 + pch * 16 + (zc & 7) * 2) = o;
    }
  }
  __syncthreads();
  // dense store: 32 lanes cover one 512B row; 1KB contiguous per instruction
#pragma unroll
  for (int i = 0; i < 8; ++i) {
    const int id = t + i * 512;
    const int rr = id >> 5, cc = id & 31;
    const int pch = (cc & 24) | ((cc ^ (rr & 7)) & 7);
    const uint4 v = *(const uint4*)(lds + rr * 512 + pch * 16);
    *(uint4*)(z + (u32)(rowBase + rr) * DD + cc * 8) = v;
  }
}

// ---------------------------------------------------------------- K2
// h1 = leaky((z[neigh1].sum + z)/6), only for rows layer 2 reads.
__global__ __launch_bounds__(256) void k2_agg1(
    const u16* __restrict__ z, const int* __restrict__ neigh1, u16* __restrict__ h1,
    const unsigned char* __restrict__ flags)
{
  const int t = threadIdx.x;
  const int row = blockIdx.x * 8 + (t >> 5);
  if (!flags[row]) return;   // half-wave uniform; no barriers in this kernel
  const int ch = t & 31;
  const u32 o0 = (u32)row * DD + ch * 8;
  uint4 a = *(const uint4*)(z + o0);
  float2 s0 = bf2f(a.x), s1 = bf2f(a.y), s2 = bf2f(a.z), s3 = bf2f(a.w);
#pragma unroll
  for (int j = 0; j < 5; ++j) {
    const int idx = neigh1[row * 5 + j];
    const uint4 v = *(const uint4*)(z + (u32)idx * DD + ch * 8);
    s0.x += bf_lo(v.x); s0.y += bf_hi(v.x);
    s1.x += bf_lo(v.y); s1.y += bf_hi(v.y);
    s2.x += bf_lo(v.z); s2.y += bf_hi(v.z);
    s3.x += bf_lo(v.w); s3.y += bf_hi(v.w);
  }
  const float sc = 1.0f / 6.0f;
  uint4 o;
  o.x = packbf2(lrelu(s0.x * sc), lrelu(s0.y * sc));
  o.y = packbf2(lrelu(s1.x * sc), lrelu(s1.y * sc));
  o.z = packbf2(lrelu(s2.x * sc), lrelu(s2.y * sc));
  o.w = packbf2(lrelu(s3.x * sc), lrelu(s3.y * sc));
  *(uint4*)(h1 + o0) = o;
}

// ---------------------------------------------------------------- K3 (fused layer2 + scores)
__global__ __launch_bounds__(512, 2) void k3_fused(
    const u16* __restrict__ h1, const u16* __restrict__ w2b, const u16* __restrict__ wcb,
    const int* __restrict__ nodes, const int* __restrict__ neigh2, float* __restrict__ out)
{
  // 0: A 8KB | 8192: B 32KB | 40960: Wc 24KB. After loop: 0..32KB = h2 tile.
  __shared__ __align__(16) unsigned char lds[65536];

  const int t = threadIdx.x;
  const int rowBase = blockIdx.x * 64;
  const int lane = t & 63, w = t >> 6;
  const int wm = w >> 2, wn = w & 3;
  const int lr = lane & 15, kg = lane >> 4;

#pragma unroll
  for (int i = 0; i < 3; ++i) {
    const int id = t + i * 512;
    uint4 v = make_uint4(0u, 0u, 0u, 0u);
    if (id < 1280) v = *(const uint4*)(wcb + (u32)id * 8);
    *(uint4*)(lds + 40960 + id * 16) = v;
  }

  const int r = t >> 3, c = t & 7;
  const int b = rowBase + r;
  u32 offA[11];
  offA[0] = (u32)nodes[b] * DD + (u32)c * 8;
#pragma unroll
  for (int j = 0; j < 10; ++j)
    offA[1 + j] = (u32)neigh2[b * 10 + j] * DD + (u32)c * 8;
  const int aW = swz(r, c);

  const u32 bofs = (u32)(w * 8 + (lane >> 3)) * DD + (u32)(lane & 7) * 8;
  unsigned char* bl0 = lds + 8192 + w * 1024;

  int aA[2][2], bA[2][4];
#pragma unroll
  for (int kk = 0; kk < 2; ++kk) {
    const int cb = kk * 4 + kg;
#pragma unroll
    for (int m = 0; m < 2; ++m) aA[kk][m] = swz(wm * 32 + m * 16 + lr, cb);
#pragma unroll
    for (int n = 0; n < 4; ++n) bA[kk][n] = 8192 + swz(wn * 64 + n * 16 + lr, cb);
  }

  f32x4 acc[2][4];
#pragma unroll
  for (int m = 0; m < 2; ++m)
#pragma unroll
    for (int n = 0; n < 4; ++n) acc[m][n] = (f32x4)0.0f;

  uint4 ag[11];
#pragma unroll
  for (int j = 0; j < 11; ++j) ag[j] = *(const uint4*)(h1 + offA[j]);

  for (int ks = 0; ks < 4; ++ks) {
    if (ks) __builtin_amdgcn_s_barrier();
    {
      float2 s0 = make_float2(0.f, 0.f), s1 = make_float2(0.f, 0.f);
      float2 s2 = make_float2(0.f, 0.f), s3 = make_float2(0.f, 0.f);
#pragma unroll
      for (int j = 0; j < 11; ++j) {
        s0.x += bf_lo(ag[j].x); s0.y += bf_hi(ag[j].x);
        s1.x += bf_lo(ag[j].y); s1.y += bf_hi(ag[j].y);
        s2.x += bf_lo(ag[j].z); s2.y += bf_hi(ag[j].z);
        s3.x += bf_lo(ag[j].w); s3.y += bf_hi(ag[j].w);
      }
      const float sc = 1.0f / 11.0f;
      uint4 o;
      o.x = packbf2(s0.x * sc, s0.y * sc);
      o.y = packbf2(s1.x * sc, s1.y * sc);
      o.z = packbf2(s2.x * sc, s2.y * sc);
      o.w = packbf2(s3.x * sc, s3.y * sc);
      *(uint4*)(lds + aW) = o;
    }
#pragma unroll
    for (int i = 0; i < 4; ++i)
      gld_lds16(w2b + bofs + (u32)i * 64 * DD + (u32)ks * 64, bl0 + i * 8192);
    __syncthreads();
    if (ks < 3) {
#pragma unroll
      for (int j = 0; j < 11; ++j)
        ag[j] = *(const uint4*)(h1 + offA[j] + (u32)(ks + 1) * 64);
    }
    __builtin_amdgcn_sched_barrier(0);
#pragma unroll
    for (int kk = 0; kk < 2; ++kk) {
      bf16x8 av[2], bv[4];
#pragma unroll
      for (int m = 0; m < 2; ++m) av[m] = *(const bf16x8*)(lds + aA[kk][m]);
#pragma unroll
      for (int n = 0; n < 4; ++n) bv[n] = *(const bf16x8*)(lds + bA[kk][n]);
#pragma unroll
      for (int m = 0; m < 2; ++m)
#pragma unroll
        for (int n = 0; n < 4; ++n)
          acc[m][n] = __builtin_amdgcn_mfma_f32_16x16x32_bf16(av[m], bv[n], acc[m][n], 0, 0, 0);
    }
  }

  __syncthreads();
#pragma unroll
  for (int m = 0; m < 2; ++m) {
#pragma unroll
    for (int j = 0; j < 4; ++j) {
      const int row = wm * 32 + m * 16 + kg * 4 + j;
#pragma unroll
      for (int n = 0; n < 4; ++n) {
        const int col = wn * 64 + n * 16 + lr;
        const int ch = col >> 3;
        const int pch = (ch & 24) | ((ch ^ row) & 7);
        *(u16*)(lds + row * 512 + pch * 16 + (col & 7) * 2) = fbits(lrelu(acc[m][n][j]));
      }
    }
  }
  __syncthreads();

  if (w < 4) {
    f32x4 acc2[3];
#pragma unroll
    for (int n = 0; n < 3; ++n) acc2[n] = (f32x4)0.0f;
    const int arow = w * 16 + lr;
#pragma unroll
    for (int ks2 = 0; ks2 < 8; ++ks2) {
      const int chb = ks2 * 4 + kg;
      const int pchA = (chb & 24) | ((chb ^ arow) & 7);
      const bf16x8 a = *(const bf16x8*)(lds + arow * 512 + pchA * 16);
#pragma unroll
      for (int n = 0; n < 3; ++n) {
        const int brow = n * 16 + lr;
        const int pchB = (chb & 24) | ((chb ^ brow) & 7);
        const bf16x8 bb = *(const bf16x8*)(lds + 40960 + brow * 512 + pchB * 16);
        acc2[n] = __builtin_amdgcn_mfma_f32_16x16x32_bf16(a, bb, acc2[n], 0, 0, 0);
      }
    }
#pragma unroll
    for (int n = 0; n < 3; ++n) {
      const int col = n * 16 + lr;
      if (col < CC) {
#pragma unroll
        for (int j = 0; j < 4; ++j) {
          const int rr = rowBase + w * 16 + kg * 4 + j;
          out[(u32)rr * CC + col] = acc2[n][j];
        }
      }
    }
  }
}

extern "C" void kernel_launch(void* const* d_in, const int* in_sizes, int n_in,
                              void* d_out, int out_size, void* d_ws, size_t ws_size,
                              hipStream_t stream) {
  const float* x    = (const float*)d_in[0];
  const float* W1   = (const float*)d_in[1];
  const float* W2   = (const float*)d_in[2];
  const float* Wc   = (const float*)d_in[3];
  const int* nodes  = (const int*)d_in[4];
  const int* neigh1 = (const int*)d_in[5];
  const int* neigh2 = (const int*)d_in[6];

  u16* z   = (u16*)d_ws;                     // 100096*256 bf16
  u16* h1  = z + (size_t)100096 * 256;       // 100096*256 bf16
  u16* w1b = h1 + (size_t)100096 * 256;      // 256x512 bf16 (chunk-swizzled)
  u16* w2b = w1b + (size_t)256 * 512;        // 256x256 bf16 (chunk-swizzled)
  u16* wcb = w2b + (size_t)256 * 256;        // 40x256 bf16 (chunk-swizzled)
  u32* flagw = (u32*)(wcb + (size_t)40 * 256);  // 25024 u32 = 100096 flag bytes
  unsigned char* flags = (unsigned char*)flagw;

  k0_cvt<<<dim3(101), dim3(256), 0, stream>>>(W1, W2, Wc, w1b, w2b, wcb, flagw);
  k0b_flags<<<dim3(704), dim3(256), 0, stream>>>(nodes, neigh2, flags);
  k1_gemm<<<dim3(782), dim3(512), 0, stream>>>(x, w1b, z);
  k2_agg1<<<dim3(12500), dim3(256), 0, stream>>>(z, neigh1, h1, flags);
  k3_fused<<<dim3(256), dim3(512), 0, stream>>>(h1, w2b, wcb, nodes, neigh2, (float*)d_out);
}

// Round 14
// 128.799 us; speedup vs baseline: 1.3324x; 1.0573x over previous
//
#include <hip/hip_runtime.h>
#include <hip/hip_bf16.h>

// SupervisedGraphSage forward. fp32 device buffers; bf16 MFMA internally.
//   z  = x @ W1^T                        [N, D]  (K1)
//   h1 = leaky((z[neigh1].sum + z)/6)    [N, D]  (K2, only referenced rows)
//   h2 = leaky((h1[neigh2].sum+h1[nodes])/11 @ W2^T); out = h2 @ Wc^T  (K3 fused)
//
// R14: K1 restructured to WAVE-PRIVATE A (16x256 wave tile). R13 analysis:
// ~7us/step vs ~0.5us compute -> waves parked at barriers; the single-buffered
// A-tile serialized A-write -> barrier -> read every step. Now each wave loads
// its own 16 x-rows' MFMA fragments directly from global (no A-LDS, no A
// barrier coupling, no redundancy); barriers guard only the B double-buffer
// (gld_lds + counted vmcnt, proven). Epilogue/K0/K2/K3 identical to R13.

#define NN 100000
#define FF 512
#define DD 256
#define BB 16384
#define CC 40

typedef __attribute__((ext_vector_type(8))) short bf16x8;
typedef __attribute__((ext_vector_type(4))) float f32x4;
typedef unsigned short u16;
typedef unsigned int u32;
typedef __attribute__((ext_vector_type(4))) u32 u32x4;

__device__ __forceinline__ float bf_lo(u32 u) { u32 v = u << 16; float f; __builtin_memcpy(&f, &v, 4); return f; }
__device__ __forceinline__ float bf_hi(u32 u) { u32 v = u & 0xffff0000u; float f; __builtin_memcpy(&f, &v, 4); return f; }
__device__ __forceinline__ float2 bf2f(u32 u) { return make_float2(bf_lo(u), bf_hi(u)); }
__device__ __forceinline__ float asf(u32 u) { float f; __builtin_memcpy(&f, &u, 4); return f; }
__device__ __forceinline__ u32 packbf2(float a, float b) {
  __hip_bfloat162 h = __float22bfloat162_rn(make_float2(a, b));
  u32 u; __builtin_memcpy(&u, &h, 4); return u;
}
__device__ __forceinline__ u16 fbits(float v) {
  __hip_bfloat16 h = __float2bfloat16(v);
  u16 u; __builtin_memcpy(&u, &h, 2); return u;
}
__device__ __forceinline__ float lrelu(float v) { return v >= 0.f ? v : 0.2f * v; }
// [R][64]-bf16 tile: byte offset of chunk c in row r, XOR-swizzled (G4).
__device__ __forceinline__ int swz(int r, int c) { return r * 128 + ((c ^ (r & 7)) << 4); }
// direct global->LDS 16B copy (dest = wave-uniform base + lane*16)
__device__ __forceinline__ void gld_lds16(const u16* g, void* l) {
  __builtin_amdgcn_global_load_lds((const __attribute__((address_space(1))) unsigned int*)g,
                                   (__attribute__((address_space(3))) unsigned int*)l, 16, 0, 0);
}
__device__ __forceinline__ u32x4 ld4(const float* p) { return *(const u32x4*)p; }

// ---------------------------------------------------------------- K0
// fp32 weights -> bf16, chunk-swizzled storage; also zero the h1-row flags.
__global__ __launch_bounds__(256) void k0_cvt(
    const float* __restrict__ W1, const float* __restrict__ W2, const float* __restrict__ Wc,
    u16* __restrict__ w1b, u16* __restrict__ w2b, u16* __restrict__ wcb,
    u32* __restrict__ flagw)
{
  const int i = blockIdx.x * 256 + threadIdx.x;
  if (i < 25024) flagw[i] = 0;   // 100096 flag bytes
  const float* src; u16* dst; int r, cc, rowE;
  if (i < 16384)      { src = W1; dst = w1b; r = i >> 6; cc = i & 63; rowE = 512; }
  else if (i < 24576) { int j = i - 16384; src = W2; dst = w2b; r = j >> 5; cc = j & 31; rowE = 256; }
  else if (i < 25856) { int j = i - 24576; src = Wc; dst = wcb; r = j >> 5; cc = j & 31; rowE = 256; }
  else return;
  const int g = cc >> 3, cp = cc & 7;
  const float* s = src + (u32)r * rowE + g * 64 + (u32)(cp ^ (r & 7)) * 8;
  const float4 v0 = *(const float4*)s;
  const float4 v1 = *(const float4*)(s + 4);
  uint4 o;
  o.x = packbf2(v0.x, v0.y); o.y = packbf2(v0.z, v0.w);
  o.z = packbf2(v1.x, v1.y); o.w = packbf2(v1.z, v1.w);
  *(uint4*)(dst + (u32)r * rowE + g * 64 + cp * 8) = o;
}

// ---------------------------------------------------------------- K0b
__global__ __launch_bounds__(256) void k0b_flags(
    const int* __restrict__ nodes, const int* __restrict__ neigh2,
    unsigned char* __restrict__ flags)
{
  const int i = blockIdx.x * 256 + threadIdx.x;
  int idx;
  if (i < BB) idx = nodes[i];
  else if (i < BB + BB * 10) idx = neigh2[i - BB];
  else return;
  flags[idx] = 1;
}

// ---------------------------------------------------------------- K1
// z = x @ W1^T. BM=128, BN=256, BK=64, 8 steps, 512 thr = 8 waves.
// Wave tile 16x256: wave w owns x-rows rowBase + w*16 + (lane&15), ALL cols.
// A: per-wave private, 4 dense 16B fp32 global loads/step (lane (lr,kg) reads
// x[row][ks*64+kk*32+kg*8 ..+8] = exactly the MFMA operand fragment), cvt in
// regs. B: [256][64]bf16 LDS dbuf via gld_lds from pre-swizzled w1b, counted
// vmcnt(8). Barriers guard ONLY B. Epilogue: swizzled LDS tile -> dense stores.
__global__ __launch_bounds__(512, 4) void k1_gemm(
    const float* __restrict__ x, const u16* __restrict__ w1b, u16* __restrict__ z)
{
  __shared__ __align__(16) unsigned char lds[65536];  // B0 @0, B1 @32768; epi reuses

  const int t = threadIdx.x;
  const int rowBase = blockIdx.x * 128;
  const int lane = t & 63, w = t >> 6;
  const int lr = lane & 15, kg = lane >> 4;

  // private A row for this lane (all n-frags share it)
  int rw = rowBase + w * 16 + lr; if (rw > NN - 1) rw = NN - 1;
  const float* xr = x + (u32)rw * FF + (u32)kg * 8;

  // B staging (R13 pattern): 4 gld_lds/wave/step, rows w*8+(lane>>3)+i*64
  const u32 bofs = (u32)(w * 8 + (lane >> 3)) * FF + (u32)(lane & 7) * 8;

  // bv base byte-addrs: row = n*16+lr -> (row&7)=lr&7; phys chunk n-independent
  int bvb[2];
#pragma unroll
  for (int kk = 0; kk < 2; ++kk)
    bvb[kk] = lr * 128 + (((kk * 4 + kg) ^ (lr & 7)) << 4);

  f32x4 acc[16];
#pragma unroll
  for (int n = 0; n < 16; ++n) acc[n] = (f32x4)0.0f;

  // prologue: A[0] (4 loads), B[0] -> buf0, B[1] -> buf1
  u32x4 pa[2][2];
#pragma unroll
  for (int kk = 0; kk < 2; ++kk) {
    pa[kk][0] = ld4(xr + kk * 32);
    pa[kk][1] = ld4(xr + kk * 32 + 4);
  }
#pragma unroll
  for (int i = 0; i < 4; ++i)
    gld_lds16(w1b + bofs + (u32)i * 64 * FF, lds + w * 1024 + i * 8192);
#pragma unroll
  for (int i = 0; i < 4; ++i)
    gld_lds16(w1b + bofs + (u32)i * 64 * FF + 64, lds + 32768 + w * 1024 + i * 8192);

#pragma unroll
  for (int ks = 0; ks < 8; ++ks) {
    // cvt A[ks] (compiler waits pa loads; also drains older B[ks] gld_lds)
    bf16x8 av[2];
#pragma unroll
    for (int kk = 0; kk < 2; ++kk) {
      u32x4 p;
      p[0] = packbf2(asf(pa[kk][0][0]), asf(pa[kk][0][1]));
      p[1] = packbf2(asf(pa[kk][0][2]), asf(pa[kk][0][3]));
      p[2] = packbf2(asf(pa[kk][1][0]), asf(pa[kk][1][1]));
      p[3] = packbf2(asf(pa[kk][1][2]), asf(pa[kk][1][3]));
      av[kk] = *(bf16x8*)&p;
    }
    if (ks < 7) {
      // issue A[ks+1]
#pragma unroll
      for (int kk = 0; kk < 2; ++kk) {
        pa[kk][0] = ld4(xr + (u32)(ks + 1) * 64 + kk * 32);
        pa[kk][1] = ld4(xr + (u32)(ks + 1) * 64 + kk * 32 + 4);
      }
      // keep A[ks+1](4)+B[ks+1](4); B[ks] drained
      asm volatile("s_waitcnt vmcnt(8)" ::: "memory");
    } else {
      asm volatile("s_waitcnt vmcnt(0)" ::: "memory");
    }
    __builtin_amdgcn_sched_barrier(0);
    __builtin_amdgcn_s_barrier();            // B[ks] visible to all waves
    __builtin_amdgcn_sched_barrier(0);

    const int bo = (ks & 1) * 32768;
#pragma unroll
    for (int kk = 0; kk < 2; ++kk)
#pragma unroll
      for (int n = 0; n < 16; ++n) {
        const bf16x8 bv = *(const bf16x8*)(lds + bo + bvb[kk] + n * 2048);
        acc[n] = __builtin_amdgcn_mfma_f32_16x16x32_bf16(bv, av[kk], acc[n], 0, 0, 0);
      }
    __builtin_amdgcn_sched_barrier(0);
    __builtin_amdgcn_s_barrier();            // all waves done reading buf[ks&1]
    __builtin_amdgcn_sched_barrier(0);
    if (ks <= 5) {                           // refill buf[ks&1] with B[ks+2]
      unsigned char* bl = lds + bo + w * 1024;
#pragma unroll
      for (int i = 0; i < 4; ++i)
        gld_lds16(w1b + bofs + (u32)i * 64 * FF + (u32)(ks + 2) * 64, bl + i * 8192);
    }
  }

  // ---- epilogue via LDS (R13-proven): swizzled [128][256]bf16 tile @0 ----
  __syncthreads();   // all B reads/writes drained; whole LDS reusable
  {
    const int zr = w * 16 + lr;              // 0..127, distinct per (w,lr)
#pragma unroll
    for (int n = 0; n < 16; ++n) {
      const int zc = n * 16 + kg * 4;        // 4 consecutive cols
      uint2 o;
      o.x = packbf2(acc[n][0], acc[n][1]);
      o.y = packbf2(acc[n][2], acc[n][3]);
      const int ch = zc >> 3;
      const int pch = (ch & 24) | ((ch ^ (zr & 7)) & 7);
      *(uint2*)(lds + zr * 512 + pch * 16 + (zc & 7) * 2) = o;
    }
  }
  __syncthreads();
  // dense store: 32 lanes cover one 512B row; 1KB contiguous per instruction
#pragma unroll
  for (int i = 0; i < 8; ++i) {
    const int id = t + i * 512;
    const int rr = id >> 5, cc = id & 31;
    const int pch = (cc & 24) | ((cc ^ (rr & 7)) & 7);
    const uint4 v = *(const uint4*)(lds + rr * 512 + pch * 16);
    *(uint4*)(z + (u32)(rowBase + rr) * DD + cc * 8) = v;
  }
}

// ---------------------------------------------------------------- K2
// h1 = leaky((z[neigh1].sum + z)/6), only for rows layer 2 reads.
__global__ __launch_bounds__(256) void k2_agg1(
    const u16* __restrict__ z, const int* __restrict__ neigh1, u16* __restrict__ h1,
    const unsigned char* __restrict__ flags)
{
  const int t = threadIdx.x;
  const int row = blockIdx.x * 8 + (t >> 5);
  if (!flags[row]) return;   // half-wave uniform; no barriers in this kernel
  const int ch = t & 31;
  const u32 o0 = (u32)row * DD + ch * 8;
  uint4 a = *(const uint4*)(z + o0);
  float2 s0 = bf2f(a.x), s1 = bf2f(a.y), s2 = bf2f(a.z), s3 = bf2f(a.w);
#pragma unroll
  for (int j = 0; j < 5; ++j) {
    const int idx = neigh1[row * 5 + j];
    const uint4 v = *(const uint4*)(z + (u32)idx * DD + ch * 8);
    s0.x += bf_lo(v.x); s0.y += bf_hi(v.x);
    s1.x += bf_lo(v.y); s1.y += bf_hi(v.y);
    s2.x += bf_lo(v.z); s2.y += bf_hi(v.z);
    s3.x += bf_lo(v.w); s3.y += bf_hi(v.w);
  }
  const float sc = 1.0f / 6.0f;
  uint4 o;
  o.x = packbf2(lrelu(s0.x * sc), lrelu(s0.y * sc));
  o.y = packbf2(lrelu(s1.x * sc), lrelu(s1.y * sc));
  o.z = packbf2(lrelu(s2.x * sc), lrelu(s2.y * sc));
  o.w = packbf2(lrelu(s3.x * sc), lrelu(s3.y * sc));
  *(uint4*)(h1 + o0) = o;
}

// ---------------------------------------------------------------- K3 (fused layer2 + scores)
__global__ __launch_bounds__(512, 2) void k3_fused(
    const u16* __restrict__ h1, const u16* __restrict__ w2b, const u16* __restrict__ wcb,
    const int* __restrict__ nodes, const int* __restrict__ neigh2, float* __restrict__ out)
{
  // 0: A 8KB | 8192: B 32KB | 40960: Wc 24KB. After loop: 0..32KB = h2 tile.
  __shared__ __align__(16) unsigned char lds[65536];

  const int t = threadIdx.x;
  const int rowBase = blockIdx.x * 64;
  const int lane = t & 63, w = t >> 6;
  const int wm = w >> 2, wn = w & 3;
  const int lr = lane & 15, kg = lane >> 4;

#pragma unroll
  for (int i = 0; i < 3; ++i) {
    const int id = t + i * 512;
    uint4 v = make_uint4(0u, 0u, 0u, 0u);
    if (id < 1280) v = *(const uint4*)(wcb + (u32)id * 8);
    *(uint4*)(lds + 40960 + id * 16) = v;
  }

  const int r = t >> 3, c = t & 7;
  const int b = rowBase + r;
  u32 offA[11];
  offA[0] = (u32)nodes[b] * DD + (u32)c * 8;
#pragma unroll
  for (int j = 0; j < 10; ++j)
    offA[1 + j] = (u32)neigh2[b * 10 + j] * DD + (u32)c * 8;
  const int aW = swz(r, c);

  const u32 bofs = (u32)(w * 8 + (lane >> 3)) * DD + (u32)(lane & 7) * 8;
  unsigned char* bl0 = lds + 8192 + w * 1024;

  int aA[2][2], bA[2][4];
#pragma unroll
  for (int kk = 0; kk < 2; ++kk) {
    const int cb = kk * 4 + kg;
#pragma unroll
    for (int m = 0; m < 2; ++m) aA[kk][m] = swz(wm * 32 + m * 16 + lr, cb);
#pragma unroll
    for (int n = 0; n < 4; ++n) bA[kk][n] = 8192 + swz(wn * 64 + n * 16 + lr, cb);
  }

  f32x4 acc[2][4];
#pragma unroll
  for (int m = 0; m < 2; ++m)
#pragma unroll
    for (int n = 0; n < 4; ++n) acc[m][n] = (f32x4)0.0f;

  uint4 ag[11];
#pragma unroll
  for (int j = 0; j < 11; ++j) ag[j] = *(const uint4*)(h1 + offA[j]);

  for (int ks = 0; ks < 4; ++ks) {
    if (ks) __builtin_amdgcn_s_barrier();
    {
      float2 s0 = make_float2(0.f, 0.f), s1 = make_float2(0.f, 0.f);
      float2 s2 = make_float2(0.f, 0.f), s3 = make_float2(0.f, 0.f);
#pragma unroll
      for (int j = 0; j < 11; ++j) {
        s0.x += bf_lo(ag[j].x); s0.y += bf_hi(ag[j].x);
        s1.x += bf_lo(ag[j].y); s1.y += bf_hi(ag[j].y);
        s2.x += bf_lo(ag[j].z); s2.y += bf_hi(ag[j].z);
        s3.x += bf_lo(ag[j].w); s3.y += bf_hi(ag[j].w);
      }
      const float sc = 1.0f / 11.0f;
      uint4 o;
      o.x = packbf2(s0.x * sc, s0.y * sc);
      o.y = packbf2(s1.x * sc, s1.y * sc);
      o.z = packbf2(s2.x * sc, s2.y * sc);
      o.w = packbf2(s3.x * sc, s3.y * sc);
      *(uint4*)(lds + aW) = o;
    }
#pragma unroll
    for (int i = 0; i < 4; ++i)
      gld_lds16(w2b + bofs + (u32)i * 64 * DD + (u32)ks * 64, bl0 + i * 8192);
    __syncthreads();
    if (ks < 3) {
#pragma unroll
      for (int j = 0; j < 11; ++j)
        ag[j] = *(const uint4*)(h1 + offA[j] + (u32)(ks + 1) * 64);
    }
    __builtin_amdgcn_sched_barrier(0);
#pragma unroll
    for (int kk = 0; kk < 2; ++kk) {
      bf16x8 av[2], bv[4];
#pragma unroll
      for (int m = 0; m < 2; ++m) av[m] = *(const bf16x8*)(lds + aA[kk][m]);
#pragma unroll
      for (int n = 0; n < 4; ++n) bv[n] = *(const bf16x8*)(lds + bA[kk][n]);
#pragma unroll
      for (int m = 0; m < 2; ++m)
#pragma unroll
        for (int n = 0; n < 4; ++n)
          acc[m][n] = __builtin_amdgcn_mfma_f32_16x16x32_bf16(av[m], bv[n], acc[m][n], 0, 0, 0);
    }
  }

  __syncthreads();
#pragma unroll
  for (int m = 0; m < 2; ++m) {
#pragma unroll
    for (int j = 0; j < 4; ++j) {
      const int row = wm * 32 + m * 16 + kg * 4 + j;
#pragma unroll
      for (int n = 0; n < 4; ++n) {
        const int col = wn * 64 + n * 16 + lr;
        const int ch = col >> 3;
        const int pch = (ch & 24) | ((ch ^ row) & 7);
        *(u16*)(lds + row * 512 + pch * 16 + (col & 7) * 2) = fbits(lrelu(acc[m][n][j]));
      }
    }
  }
  __syncthreads();

  if (w < 4) {
    f32x4 acc2[3];
#pragma unroll
    for (int n = 0; n < 3; ++n) acc2[n] = (f32x4)0.0f;
    const int arow = w * 16 + lr;
#pragma unroll
    for (int ks2 = 0; ks2 < 8; ++ks2) {
      const int chb = ks2 * 4 + kg;
      const int pchA = (chb & 24) | ((chb ^ arow) & 7);
      const bf16x8 a = *(const bf16x8*)(lds + arow * 512 + pchA * 16);
#pragma unroll
      for (int n = 0; n < 3; ++n) {
        const int brow = n * 16 + lr;
        const int pchB = (chb & 24) | ((chb ^ brow) & 7);
        const bf16x8 bb = *(const bf16x8*)(lds + 40960 + brow * 512 + pchB * 16);
        acc2[n] = __builtin_amdgcn_mfma_f32_16x16x32_bf16(a, bb, acc2[n], 0, 0, 0);
      }
    }
#pragma unroll
    for (int n = 0; n < 3; ++n) {
      const int col = n * 16 + lr;
      if (col < CC) {
#pragma unroll
        for (int j = 0; j < 4; ++j) {
          const int rr = rowBase + w * 16 + kg * 4 + j;
          out[(u32)rr * CC + col] = acc2[n][j];
        }
      }
    }
  }
}

extern "C" void kernel_launch(void* const* d_in, const int* in_sizes, int n_in,
                              void* d_out, int out_size, void* d_ws, size_t ws_size,
                              hipStream_t stream) {
  const float* x    = (const float*)d_in[0];
  const float* W1   = (const float*)d_in[1];
  const float* W2   = (const float*)d_in[2];
  const float* Wc   = (const float*)d_in[3];
  const int* nodes  = (const int*)d_in[4];
  const int* neigh1 = (const int*)d_in[5];
  const int* neigh2 = (const int*)d_in[6];

  u16* z   = (u16*)d_ws;                     // 100096*256 bf16
  u16* h1  = z + (size_t)100096 * 256;       // 100096*256 bf16
  u16* w1b = h1 + (size_t)100096 * 256;      // 256x512 bf16 (chunk-swizzled)
  u16* w2b = w1b + (size_t)256 * 512;        // 256x256 bf16 (chunk-swizzled)
  u16* wcb = w2b + (size_t)256 * 256;        // 40x256 bf16 (chunk-swizzled)
  u32* flagw = (u32*)(wcb + (size_t)40 * 256);  // 25024 u32 = 100096 flag bytes
  unsigned char* flags = (unsigned char*)flagw;

  k0_cvt<<<dim3(101), dim3(256), 0, stream>>>(W1, W2, Wc, w1b, w2b, wcb, flagw);
  k0b_flags<<<dim3(704), dim3(256), 0, stream>>>(nodes, neigh2, flags);
  k1_gemm<<<dim3(782), dim3(512), 0, stream>>>(x, w1b, z);
  k2_agg1<<<dim3(12500), dim3(256), 0, stream>>>(z, neigh1, h1, flags);
  k3_fused<<<dim3(256), dim3(512), 0, stream>>>(h1, w2b, wcb, nodes, neigh2, (float*)d_out);
}